// Round 16
// baseline (270.167 us; speedup 1.0000x reference)
//
#include <hip/hip_runtime.h>
#include <stdint.h>

#define S_LEN 2048
#define DIMM  2048
#define NH    16
#define NKV   2

typedef __attribute__((ext_vector_type(8)))  short s16x8;
typedef __attribute__((ext_vector_type(8)))  unsigned short u16x8;
typedef __attribute__((ext_vector_type(4)))  float f32x4;
typedef __attribute__((ext_vector_type(16))) float f32x16;
typedef __attribute__((ext_vector_type(4)))  unsigned int u32x4;

__device__ __forceinline__ unsigned short f2bf(float f){
  unsigned int u = __builtin_bit_cast(unsigned int, f);
  u += 0x7fffu + ((u >> 16) & 1u);
  return (unsigned short)(u >> 16);
}

__device__ __forceinline__ float bf2f(unsigned short u){
  return __builtin_bit_cast(float, ((unsigned int)u) << 16);
}

__device__ __forceinline__ unsigned int cvtpk(float lo, float hi){
  unsigned int r;
  asm("v_cvt_pk_bf16_f32 %0, %1, %2" : "=v"(r) : "v"(lo), "v"(hi));
  return r;
}

__device__ __forceinline__ void gload16(const void* g, void* l){
  __builtin_amdgcn_global_load_lds(
      (const __attribute__((address_space(1))) unsigned int*)g,
      (__attribute__((address_space(3))) unsigned int*)l, 16, 0, 0);
}

// ---------------- fused fp32 -> bf16 convert for all 5 tensors ----------------
__global__ __launch_bounds__(256) void cvt_all(const float* __restrict__ x,
    const float* __restrict__ wq, const float* __restrict__ wk,
    const float* __restrict__ wv, const float* __restrict__ wo,
    unsigned short* __restrict__ xb, unsigned short* __restrict__ wqkvb,
    unsigned short* __restrict__ wob){
  long gid = (long)blockIdx.x * 256 + threadIdx.x;
  const float* src; unsigned short* dst; long off;
  if (gid < 1048576)      { src = x;  dst = xb;              off = gid; }
  else if (gid < 1572864) { src = wq; dst = wqkvb;           off = gid - 1048576; }
  else if (gid < 1638400) { src = wk; dst = wqkvb + 4194304; off = gid - 1572864; }
  else if (gid < 1703936) { src = wv; dst = wqkvb + 4718592; off = gid - 1638400; }
  else                    { src = wo; dst = wob;             off = gid - 1703936; }
  long i = off * 8;
  const float4* s4 = (const float4*)(src + i);
  float4 a = s4[0], b = s4[1];
  u16x8 o;
  o[0]=f2bf(a.x); o[1]=f2bf(a.y); o[2]=f2bf(a.z); o[3]=f2bf(a.w);
  o[4]=f2bf(b.x); o[5]=f2bf(b.y); o[6]=f2bf(b.z); o[7]=f2bf(b.w);
  *(u16x8*)(dst + i) = o;
}

// ---------------- C = A(bf16,[M,K]) @ W(bf16,[N,K])^T, out fp32 or bf16 ----------------
template<bool OBF16>
__global__ __launch_bounds__(256) void gemm_bt(const unsigned short* __restrict__ A,
                                               const unsigned short* __restrict__ W,
                                               void* __restrict__ Cv,
                                               int M, int N, int K){
  __shared__ __attribute__((aligned(16))) unsigned short As[128*64];
  __shared__ __attribute__((aligned(16))) unsigned short Bs[128*64];
  const int t = threadIdx.x;
  const int lane = t & 63, wave = t >> 6;
  const int l15 = lane & 15, g = lane >> 4;
  const int lid = blockIdx.y * gridDim.x + blockIdx.x;
  const int cpx = (gridDim.x * gridDim.y) >> 3;
  const int swz = (lid & 7) * cpx + (lid >> 3);
  const int m0 = (swz / gridDim.x) * 128, n0 = (swz % gridDim.x) * 128;
  const int wm = (wave >> 1) * 64, wn = (wave & 1) * 64;
  const int srow = t >> 3, sdblk = t & 7;
  const long ldsoff = (long)(t >> 6) * 1024;
  f32x4 acc[4][4] = {};
  for (int k0 = 0; k0 < K; k0 += 64){
    __syncthreads();
    #pragma unroll
    for (int r = 0; r < 4; ++r){
      int row = r*32 + srow;
      int db  = sdblk ^ (row & 7);
      gload16(A + (long)(m0+row)*K + k0 + db*8, (char*)As + r*4096 + ldsoff);
    }
    #pragma unroll
    for (int r = 0; r < 4; ++r){
      int row = r*32 + srow;
      int db  = sdblk ^ (row & 7);
      gload16(W + (long)(n0+row)*K + k0 + db*8, (char*)Bs + r*4096 + ldsoff);
    }
    __syncthreads();
    s16x8 af[4][2], bfr[4][2];
    #pragma unroll
    for (int mi = 0; mi < 4; ++mi)
      #pragma unroll
      for (int kc = 0; kc < 2; ++kc){
        int row = wm + mi*16 + l15;
        int db = (kc*4 + g) ^ (row & 7);
        af[mi][kc] = *(const s16x8*)(As + row*64 + db*8);
      }
    #pragma unroll
    for (int ni = 0; ni < 4; ++ni)
      #pragma unroll
      for (int kc = 0; kc < 2; ++kc){
        int row = wn + ni*16 + l15;
        int db = (kc*4 + g) ^ (row & 7);
        bfr[ni][kc] = *(const s16x8*)(Bs + row*64 + db*8);
      }
    #pragma unroll
    for (int mi = 0; mi < 4; ++mi)
      #pragma unroll
      for (int ni = 0; ni < 4; ++ni)
        #pragma unroll
        for (int kc = 0; kc < 2; ++kc)
          acc[mi][ni] = __builtin_amdgcn_mfma_f32_16x16x32_bf16(af[mi][kc], bfr[ni][kc], acc[mi][ni], 0, 0, 0);
  }
  #pragma unroll
  for (int mi = 0; mi < 4; ++mi)
    #pragma unroll
    for (int ni = 0; ni < 4; ++ni)
      #pragma unroll
      for (int rg = 0; rg < 4; ++rg){
        int row = m0 + wm + mi*16 + g*4 + rg;
        int col = n0 + wn + ni*16 + l15;
        if (OBF16)
          ((unsigned short*)Cv)[(long)row*N + col] = f2bf(acc[mi][ni][rg]);
        else
          ((float*)Cv)[(long)row*N + col] = acc[mi][ni][rg];
      }
}

// ---------------- RMSNorm + rotary for Q and K (bf16 qkv input) ----------------
__global__ __launch_bounds__(256) void normrope(const unsigned short* __restrict__ qkv,
    const float* __restrict__ cosb, const float* __restrict__ sinb,
    const float* __restrict__ qg, const float* __restrict__ kg,
    unsigned short* __restrict__ q_attn, unsigned short* __restrict__ k_attn){
  int wave = threadIdx.x >> 6, lane = threadIdx.x & 63;
  int rid = blockIdx.x * 4 + wave;
  int d0 = lane * 2;
  const unsigned short* src; unsigned short* dst; const float* gm; float sc; int s;
  if (rid < 2*S_LEN*NH){
    int bs = rid >> 4, h = rid & 15;
    int b = bs >> 11; s = bs & 2047;
    src = qkv + (long)bs*2560 + h*128;
    dst = q_attn + ((long)(b*NH + h)*S_LEN + s)*128;
    gm = qg; sc = 0.08838834764831845f * 1.4426950408889634f;
  } else {
    int r2 = rid - 2*S_LEN*NH;
    int bs = r2 >> 1, kv = r2 & 1;
    int b = bs >> 11; s = bs & 2047;
    src = qkv + (long)bs*2560 + 2048 + kv*128;
    dst = k_attn + ((long)(b*NKV + kv)*S_LEN + s)*128;
    gm = kg; sc = 1.0f;
  }
  unsigned int xw = *(const unsigned int*)(src + d0);
  float x0 = bf2f((unsigned short)(xw & 0xffff));
  float x1 = bf2f((unsigned short)(xw >> 16));
  float ss = x0*x0 + x1*x1;
  #pragma unroll
  for (int m = 1; m < 64; m <<= 1) ss += __shfl_xor(ss, m);
  float r = rsqrtf(ss * (1.0f/128.0f) + 1e-6f);
  float2 gv = *(const float2*)(gm + d0);
  float n0 = x0 * r * gv.x, n1 = x1 * r * gv.y;
  float p0 = __shfl_xor(n0, 32), p1 = __shfl_xor(n1, 32);
  float sgn = (d0 < 64) ? -1.f : 1.f;
  float2 c  = *(const float2*)(cosb + (long)s*128 + d0);
  float2 sn = *(const float2*)(sinb + (long)s*128 + d0);
  float o0 = (n0*c.x + sgn*p0*sn.x) * sc;
  float o1 = (n1*c.y + sgn*p1*sn.y) * sc;
  unsigned int pk = (unsigned int)f2bf(o0) | ((unsigned int)f2bf(o1) << 16);
  *(unsigned int*)(dst + d0) = pk;
}

// ---------------- V: bf16 qkv cols -> [B,KV,128,S] (transposed) ----------------
__global__ __launch_bounds__(256) void vtrans(const unsigned short* __restrict__ qkv,
                                              unsigned short* __restrict__ v_t){
  __shared__ __attribute__((aligned(16))) unsigned short lds[128*72];
  int bid = blockIdx.x;
  int s0 = (bid & 31) * 64;
  int kv = (bid >> 5) & 1;
  int b  = bid >> 6;
  int t = threadIdx.x;
  #pragma unroll
  for (int it = 0; it < 32; ++it){
    int idx = it*256 + t;
    int s = idx >> 7, d = idx & 127;
    lds[d*72 + s] = qkv[(long)(b*S_LEN + s0 + s)*2560 + 2304 + kv*128 + d];
  }
  __syncthreads();
  #pragma unroll
  for (int it = 0; it < 4; ++it){
    int c = it*256 + t;
    int d = c >> 3, s8 = c & 7;
    u16x8 vv = *(const u16x8*)(lds + d*72 + s8*8);
    *(u16x8*)(v_t + ((long)(b*NKV + kv)*128 + d)*S_LEN + s0 + s8*8) = vv;
  }
}

// ---------------- flash attention: barrier-free counted-vmcnt, 1-wave blocks ----------------
// grid 2048 = 64 qsb (LPT desc) x 32 (b,h); block 64 = 1 wave x 32 q-rows; KVB=32.
// Wave-private double-buffered K (16KB LDS -> 8 blocks/CU). NO __syncthreads anywhere:
// ordering purely via counted s_waitcnt vmcnt(N) (FIFO: at QK, ops newer than stage(t)
// are V(t)=8 + stage(t+1)=8 -> vmcnt(16); last iter vmcnt(8)). sched_barrier(0) pins
// the ds_reads behind the wait (rule-18 hazard). Body = r15-verified math at KVB=32.
__global__ __launch_bounds__(64) void attn_fwd(const unsigned short* __restrict__ q_attn,
    const unsigned short* __restrict__ k_attn, const unsigned short* __restrict__ v_t,
    unsigned short* __restrict__ attn_out, const int* __restrict__ pp){
  __shared__ __attribute__((aligned(16))) unsigned short Ks[2][32*128];
  const int p = pp[0];
  int bid = blockIdx.x;
  int qsb = 63 - (bid >> 5);         // LPT: longest chains dispatch first
  int bh = bid & 31;
  int h = bh & 15, b = bh >> 4;
  int kvh = h >> 3;
  int lane = threadIdx.x & 63;
  int l31 = lane & 31, hi = lane >> 5;
  int qw0 = qsb * 32;                // this wave's 32 q-rows
  const int q = qw0 + l31;           // this lane's q-row (pair with lane^32)
  const unsigned short* qb = q_attn + ((long)(b*NH + h)*S_LEN + q)*128 + hi*8;
  s16x8 qf[8];
  #pragma unroll
  for (int m = 0; m < 8; ++m) qf[m] = *(const s16x8*)(qb + m*16);
  f32x16 O[4] = {};
  float mr = -3e38f, lr = 0.f;
  int kv_end = (qw0 + 31 < p) ? ((p > qw0 + 32) ? p : qw0 + 32) : (qw0 + 32);
  int n_w = (kv_end + 31) >> 5;
  const unsigned short* kb0 = k_attn + ((long)(b*NKV + kvh)*S_LEN)*128;
  const unsigned short* vb0 = v_t + ((long)(b*NKV + kvh)*128)*S_LEN;
  const int srow = lane >> 4, sunit = lane & 15;   // staging: 4 rows x 16 units per pass
  const unsigned short* vbase = vb0 + (long)l31*S_LEN + hi*8;

  // prologue: stage tile 0 into Ks[0] (pre-swizzled global src, linear LDS dest)
  #pragma unroll
  for (int r = 0; r < 8; ++r){
    int row = r*4 + srow;
    int un  = sunit ^ (row & 15);
    gload16(kb0 + (long)row*128 + un*8, (char*)Ks[0] + r*1024);
  }
  asm volatile("s_waitcnt vmcnt(0)" ::: "memory");
  __builtin_amdgcn_sched_barrier(0);
  int buf = 0;

  #pragma unroll 1
  for (int ti = 0; ti < n_w; ++ti){
    int j0 = ti * 32;
    // V fragments for this tile (latency hides under QK+softmax)
    s16x8 vf[4][2];
    #pragma unroll
    for (int dt = 0; dt < 4; ++dt)
      #pragma unroll
      for (int km = 0; km < 2; ++km)
        vf[dt][km] = *(const s16x8*)(vbase + (long)dt*32*S_LEN + j0 + km*16);
    // stage next K tile; counted wait so stage(t) is landed but 16 loads stay in flight
    if (ti + 1 < n_w){
      const unsigned short* kb = kb0 + (long)(j0 + 32)*128;
      char* dst = (char*)Ks[buf^1];
      #pragma unroll
      for (int r = 0; r < 8; ++r){
        int row = r*4 + srow;
        int un  = sunit ^ (row & 15);
        gload16(kb + (long)row*128 + un*8, dst + r*1024);
      }
      asm volatile("s_waitcnt vmcnt(16)" ::: "memory");
    } else {
      asm volatile("s_waitcnt vmcnt(8)" ::: "memory");
    }
    __builtin_amdgcn_sched_barrier(0);
    // swapped QK^T: sa = mfma(K_frag, Q_frag) -> D[krow][q]
    const unsigned short* ksc = Ks[buf];
    f32x16 sa = {};
    __builtin_amdgcn_s_setprio(1);
    #pragma unroll
    for (int m = 0; m < 8; ++m){
      int un = (2*m + hi) ^ (l31 & 15);
      s16x8 kf = *(const s16x8*)(ksc + l31*128 + un*8);
      sa = __builtin_amdgcn_mfma_f32_32x32x16_bf16(kf, qf[m], sa, 0, 0, 0);
    }
    __builtin_amdgcn_s_setprio(0);
    // mask + in-lane row max (16 scores here; other 16 in lane^32)
    float tm = -3e38f;
    bool full = (j0 + 31 <= qw0) || ((qw0 + 31 < p) && (j0 + 31 < p));
    if (full){
      #pragma unroll
      for (int rg = 0; rg < 16; ++rg) tm = fmaxf(tm, sa[rg]);
    } else {
      #pragma unroll
      for (int rg = 0; rg < 16; ++rg){
        int j = j0 + (rg & 3) + 8*(rg >> 2) + 4*hi;
        bool ok = (j <= q) || ((q < p) && (j < p));
        float sv = ok ? sa[rg] : -3e38f;
        sa[rg] = sv;
        tm = fmaxf(tm, sv);
      }
    }
    tm = fmaxf(tm, __shfl_xor(tm, 32));
    // online softmax (log2 domain; scale*log2e folded into Q)
    if (!__all(tm <= mr + 8.0f)){      // T13 defer-max
      float nm = fmaxf(mr, tm);
      float sfv = exp2f(mr - nm);
      mr = nm;
      lr *= sfv;
      float sfO[16];
      #pragma unroll
      for (int rg = 0; rg < 16; ++rg){
        int qr = (rg & 3) + 8*(rg >> 2) + 4*hi;
        sfO[rg] = __shfl(sfv, qr | (lane & 32));
      }
      #pragma unroll
      for (int dt = 0; dt < 4; ++dt)
        #pragma unroll
        for (int rg = 0; rg < 16; ++rg) O[dt][rg] *= sfO[rg];
    }
    float rs = 0.f;
    #pragma unroll
    for (int rg = 0; rg < 16; ++rg){
      float e = exp2f(sa[rg] - mr);
      sa[rg] = e;
      rs += e;
    }
    rs += __shfl_xor(rs, 32);
    lr += rs;
    // P -> PV A-frags: per km, 4 cvt_pk + 2 permlane32_swap; then 4 MFMA
    __builtin_amdgcn_s_setprio(1);
    #pragma unroll
    for (int km = 0; km < 2; ++km){
      int base = km * 8;
      unsigned int a0 = cvtpk(sa[base+0], sa[base+1]);
      unsigned int b0 = cvtpk(sa[base+4], sa[base+5]);
      asm("v_permlane32_swap_b32 %0, %1" : "+v"(a0), "+v"(b0));
      unsigned int a1 = cvtpk(sa[base+2], sa[base+3]);
      unsigned int b1 = cvtpk(sa[base+6], sa[base+7]);
      asm("v_permlane32_swap_b32 %0, %1" : "+v"(a1), "+v"(b1));
      u32x4 w; w[0] = a0; w[1] = a1; w[2] = b0; w[3] = b1;
      s16x8 pf = __builtin_bit_cast(s16x8, w);
      #pragma unroll
      for (int dt = 0; dt < 4; ++dt)
        O[dt] = __builtin_amdgcn_mfma_f32_32x32x16_bf16(pf, vf[dt][km], O[dt], 0, 0, 0);
    }
    __builtin_amdgcn_s_setprio(0);
    buf ^= 1;
  }
  // epilogue: redistribute 1/lr (q=l31 domain) to O rows, write bf16
  float inv = 1.0f / lr;
  float invO[16];
  #pragma unroll
  for (int rg = 0; rg < 16; ++rg){
    int qr = (rg & 3) + 8*(rg >> 2) + 4*hi;
    invO[rg] = __shfl(inv, qr | (lane & 32));
  }
  #pragma unroll
  for (int dt = 0; dt < 4; ++dt)
    #pragma unroll
    for (int rg = 0; rg < 16; ++rg){
      int row = qw0 + (rg & 3) + 8*(rg >> 2) + 4*hi;
      int col = h*128 + dt*32 + l31;
      attn_out[(long)(b*S_LEN + row)*DIMM + col] = f2bf(O[dt][rg]*invO[rg]);
    }
}

extern "C" void kernel_launch(void* const* d_in, const int* in_sizes, int n_in,
                              void* d_out, int out_size, void* d_ws, size_t ws_size,
                              hipStream_t stream){
  const float* x    = (const float*)d_in[0];
  const float* cosb = (const float*)d_in[1];
  const float* sinb = (const float*)d_in[2];
  const float* wq   = (const float*)d_in[3];
  const float* wk   = (const float*)d_in[4];
  const float* wv   = (const float*)d_in[5];
  const float* wo   = (const float*)d_in[6];
  const float* qg   = (const float*)d_in[7];
  const float* kg   = (const float*)d_in[8];
  const int*   pp   = (const int*)d_in[9];

  char* ws = (char*)d_ws;
  unsigned short* xb    = (unsigned short*)(ws);                 // 4096x2048 bf16
  unsigned short* wqkvb = (unsigned short*)(ws + 16777216);      // 2560x2048 bf16
  unsigned short* wob   = (unsigned short*)(ws + 27262976);      // 2048x2048 bf16
  unsigned short* qkvb  = (unsigned short*)(ws + 35651584);      // 4096x2560 bf16
  unsigned short* qat   = (unsigned short*)(ws + 77594624);      // [B,16,S,128]
  unsigned short* kat   = (unsigned short*)(ws + 94371840);      // [B,2,S,128]
  unsigned short* vt    = (unsigned short*)(ws + 96468992);      // [B,2,128,S]
  unsigned short* aout  = (unsigned short*)(ws + 98566144);      // [B,S,2048]

  cvt_all<<<8704, 256, 0, stream>>>(x, wq, wk, wv, wo, xb, wqkvb, wob);

  gemm_bt<true><<<dim3(2560/128, 4096/128), 256, 0, stream>>>(xb, wqkvb, qkvb, 4096, 2560, 2048);
  normrope<<<73728/4, 256, 0, stream>>>(qkvb, cosb, sinb, qg, kg, qat, kat);
  vtrans<<<128, 256, 0, stream>>>(qkvb, vt);
  attn_fwd<<<2048, 64, 0, stream>>>(qat, kat, vt, aout, pp);
  gemm_bt<false><<<dim3(2048/128, 4096/128), 256, 0, stream>>>(aout, wob, d_out, 4096, 2048, 2048);
}